// Round 7
// baseline (168.779 us; speedup 1.0000x reference)
//
#include <hip/hip_runtime.h>
#include <hip/hip_bf16.h>

// Problem constants (B=1 folded out)
constexpr int T = 8;     // frames
constexpr int C = 128;   // input channels
constexpr int N = 4096;  // H*W positions
constexpr int F = 64;    // feature dim

typedef __bf16 bf16x8 __attribute__((ext_vector_type(8)));
typedef __bf16 bf16x4 __attribute__((ext_vector_type(4)));
typedef __bf16 bf16x2 __attribute__((ext_vector_type(2)));
typedef float  f32x4  __attribute__((ext_vector_type(4)));
typedef float  f32x16 __attribute__((ext_vector_type(16)));

// ---------------------------------------------------------------------------
// Kernel 0 (fused): zero d_out (attn accumulates with atomics) + convert
// W1/W2/W3 (fp32 [F][C]) to bf16 packed [3][F][C]. Grid = 2048 blocks covers
// the T*F*N/4 float4 zero-stores; first 24576 threads also convert W.
// ---------------------------------------------------------------------------
__global__ __launch_bounds__(256) void setup_kernel(
    const float* __restrict__ W1, const float* __restrict__ W2,
    const float* __restrict__ W3, __bf16* __restrict__ Wb,
    float* __restrict__ out)
{
    int i = blockIdx.x * 256 + threadIdx.x;
    ((f32x4*)out)[i] = (f32x4){0.f, 0.f, 0.f, 0.f};
    if (i < 3 * F * C) {
        int p = i >> 13, r = i & 8191;
        const float* W = (p == 0) ? W1 : (p == 1) ? W2 : W3;
        Wb[i] = (__bf16)W[r];
    }
}

// ---------------------------------------------------------------------------
// Kernel 1: projections, split by projection for latency overlap.
// blockIdx.y = pj in {0:Q, 1:K, 2:G}; grid (512, 3) = 1536 blocks (6/CU vs
// the old 2/CU). Each block stages only the X it needs (half the staging of
// the fused version) and runs ONE short GEMM:
//   Q,K: D[m=f][n'=n] = W · X^T -> [n][F], b64 stores over f
//   G:   D[m=n][n'=f] = X^T · W3 -> [f][N], b64 stores over n
// ---------------------------------------------------------------------------
__global__ __launch_bounds__(256) void proj_kernel(
    const float* __restrict__ x1, const float* __restrict__ x2,
    const __bf16* __restrict__ Wb,
    const float* __restrict__ b1, const float* __restrict__ b2,
    const float* __restrict__ b3,
    __bf16* __restrict__ Qb, __bf16* __restrict__ Kb, __bf16* __restrict__ Gw)
{
    const int pj = blockIdx.y;        // 0=Q, 1=K, 2=G
    const int t  = blockIdx.x >> 6;
    const int nb = blockIdx.x & 63;
    const int n0 = nb * 64;

    constexpr int XS = 136;           // 272B rows (16B aligned)
    __shared__ __bf16 Xt[64 * XS];    // X^T tile: [n_local][c]

    const float* X = (pj == 1) ? x2 : x1;

    const int tid = threadIdx.x;
    const int ng  = tid & 15;         // n-block: n = ng*4 + j
    const int cgi = tid >> 4;         // c-group: c = cgi*4 (+64 per pass)

#pragma unroll
    for (int pass = 0; pass < 2; ++pass) {
        const int c0 = cgi * 4 + pass * 64;
        const size_t base = ((size_t)t * C + c0) * (size_t)N + n0 + ng * 4;
        f32x4 v[4];
#pragma unroll
        for (int i = 0; i < 4; ++i)
            v[i] = *(const f32x4*)&X[base + (size_t)i * N];
#pragma unroll
        for (int j = 0; j < 4; ++j) {
            bf16x4 o;
#pragma unroll
            for (int i = 0; i < 4; ++i) o[i] = (__bf16)v[i][j];
            *(bf16x4*)&Xt[(ng * 4 + j) * XS + c0] = o;
        }
    }
    __syncthreads();

    const int wave = tid >> 6, lane = tid & 63;
    const int quad = lane >> 4, l16 = lane & 15;

    // X^T fragments: lane holds 8 c-contiguous elems of row n = wave*16+l16
    bf16x8 a[4];
#pragma unroll
    for (int cc = 0; cc < 4; ++cc)
        a[cc] = *(const bf16x8*)&Xt[(wave * 16 + l16) * XS + cc * 32 + quad * 8];

    const __bf16* W = Wb + (size_t)pj * F * C;

    if (pj < 2) {
        // ---- Q or K: D[m=f][n'=n] = W · X^T ----
        const float* bias = pj ? b2 : b1;
        __bf16*      O    = pj ? Kb : Qb;

        f32x4 acc[4];
#pragma unroll
        for (int ft = 0; ft < 4; ++ft) acc[ft] = (f32x4){0.f, 0.f, 0.f, 0.f};
#pragma unroll
        for (int cc = 0; cc < 4; ++cc) {
#pragma unroll
            for (int ft = 0; ft < 4; ++ft) {
                bf16x8 wf = *(const bf16x8*)&W[(ft * 16 + l16) * C + cc * 32 + quad * 8];
                acc[ft] = __builtin_amdgcn_mfma_f32_16x16x32_bf16(wf, a[cc], acc[ft], 0, 0, 0);
            }
        }
        // D: col = n = wave*16+l16, row = f = ft*16 + quad*4 + r (contiguous)
        const int n = n0 + wave * 16 + l16;
#pragma unroll
        for (int ft = 0; ft < 4; ++ft) {
            const int f0 = ft * 16 + quad * 4;
            f32x4 bv = *(const f32x4*)&bias[f0];
            bf16x4 o;
#pragma unroll
            for (int r = 0; r < 4; ++r) o[r] = (__bf16)(acc[ft][r] + bv[r]);
            *(bf16x4*)&O[((size_t)t * N + n) * F + f0] = o;
        }
    } else {
        // ---- G: D[m=n][n'=f] = X^T · W3 ----
        f32x4 acc[4];
#pragma unroll
        for (int ft = 0; ft < 4; ++ft) acc[ft] = (f32x4){0.f, 0.f, 0.f, 0.f};
#pragma unroll
        for (int cc = 0; cc < 4; ++cc) {
#pragma unroll
            for (int ft = 0; ft < 4; ++ft) {
                bf16x8 wf = *(const bf16x8*)&W[(ft * 16 + l16) * C + cc * 32 + quad * 8];
                acc[ft] = __builtin_amdgcn_mfma_f32_16x16x32_bf16(a[cc], wf, acc[ft], 0, 0, 0);
            }
        }
        // D: col = f = ft*16+l16, row = n = wave*16 + quad*4 + r (contiguous)
        const int nr0 = n0 + wave * 16 + quad * 4;
#pragma unroll
        for (int ft = 0; ft < 4; ++ft) {
            const int f = ft * 16 + l16;
            const float bv = b3[f];
            bf16x4 o;
#pragma unroll
            for (int r = 0; r < 4; ++r) o[r] = (__bf16)(acc[ft][r] + bv);
            *(bf16x4*)&Gw[((size_t)t * F + f) * (size_t)N + nr0] = o;
        }
    }
}

// ---------------------------------------------------------------------------
// Kernel 2: O[t][f][q] += sum_key relu(Q[q]·K[key]) * G[key][f]
//
// R4-verified structure (LDS-staged, 32x32x16 MFMA, in-register S via
// relu+pack+v_permlane32_swap; bank conflicts = 0). Only change vs R4:
// KSPLIT 4 -> 8. Grid 2048 -> 6-8 blocks/CU (24-32 waves/CU): the R6 pipe
// audit showed time ~= SUM of pipe busy times (all pipes ~25%), i.e. pure
// latency serialization -> raise TLP so different waves' S-chain / pack /
// staging interleave on each SIMD. Cost: atomic write traffic 32->64 MB.
// ---------------------------------------------------------------------------
constexpr int KSPLIT = 8;

__global__ __launch_bounds__(256) void attn_kernel(
    const __bf16* __restrict__ Qb, const __bf16* __restrict__ Kb,
    const __bf16* __restrict__ Gw, float* __restrict__ out)
{
    const int ks = blockIdx.x & (KSPLIT - 1);
    const int qb = (blockIdx.x / KSPLIT) & 31;   // N/128 = 32 q-blocks
    const int t  = blockIdx.x / (KSPLIT * 32);
    const int q0 = qb * 128;

    constexpr int KS = 72;              // bf16 stride (144B rows, 16B aligned)
    __shared__ __bf16 Kt[64 * KS];      // K tile [key][f]
    __shared__ __bf16 Gt[64 * KS];      // G tile [f][key]

    const int tid = threadIdx.x, wave = tid >> 6, lane = tid & 63;
    const int m32 = lane & 31, hi = lane >> 5;

    // Q B-frags (32x32x16): lane holds Q[q = q0+wave*32+m32][f = fc*16+hi*8+j]
    bf16x8 qf[4];
    {
        const __bf16* qrow = &Qb[((size_t)t * N + q0 + wave * 32 + m32) * F + hi * 8];
#pragma unroll
        for (int fc = 0; fc < 4; ++fc)
            qf[fc] = *(const bf16x8*)(qrow + fc * 16);
    }

    f32x16 oacc[2];   // [f-tile]; D: col=q=m32, row=f=ft*32+(r&3)+8*(r>>2)+4*hi
#pragma unroll
    for (int ft = 0; ft < 2; ++ft)
#pragma unroll
        for (int r = 0; r < 16; ++r) oacc[ft][r] = 0.f;

    const int kb_lo = ks * (N / 64 / KSPLIT);
    const int kb_hi = kb_lo + (N / 64 / KSPLIT);

    // staging unit: u in {tid, tid+256}; r8 = u>>3 (row), c8 = (u&7)*8 (col)
    const int r8a = tid >> 3,          c8a = (tid & 7) * 8;
    const int r8b = (tid + 256) >> 3,  c8b = c8a;

    // prefetch tile kb_lo into registers
    bf16x8 kv0, kv1, gv0, gv1;
    {
        const int k0 = kb_lo * 64;
        kv0 = *(const bf16x8*)&Kb[((size_t)t * N + k0 + r8a) * F + c8a];
        kv1 = *(const bf16x8*)&Kb[((size_t)t * N + k0 + r8b) * F + c8b];
        gv0 = *(const bf16x8*)&Gw[((size_t)t * F + r8a) * (size_t)N + k0 + c8a];
        gv1 = *(const bf16x8*)&Gw[((size_t)t * F + r8b) * (size_t)N + k0 + c8b];
    }

    for (int kb = kb_lo; kb < kb_hi; ++kb) {
        __syncthreads();   // previous tile's LDS reads done
        *(bf16x8*)&Kt[r8a * KS + c8a] = kv0;
        *(bf16x8*)&Kt[r8b * KS + c8b] = kv1;
        *(bf16x8*)&Gt[r8a * KS + c8a] = gv0;
        *(bf16x8*)&Gt[r8b * KS + c8b] = gv1;
        __syncthreads();

        if (kb + 1 < kb_hi) {   // prefetch next tile (overlaps with compute)
            const int k0 = (kb + 1) * 64;
            kv0 = *(const bf16x8*)&Kb[((size_t)t * N + k0 + r8a) * F + c8a];
            kv1 = *(const bf16x8*)&Kb[((size_t)t * N + k0 + r8b) * F + c8b];
            gv0 = *(const bf16x8*)&Gw[((size_t)t * F + r8a) * (size_t)N + k0 + c8a];
            gv1 = *(const bf16x8*)&Gw[((size_t)t * F + r8b) * (size_t)N + k0 + c8b];
        }

        // ---- S + pack: per 32-key block, Sᵀ stays in registers ----
        bf16x8 ps[4];   // PV B-frags: ps[kt*2+kc] = keys kt*32+kc*16+hi*8+(0..7)
#pragma unroll
        for (int kt = 0; kt < 2; ++kt) {
            f32x16 s;
#pragma unroll
            for (int r = 0; r < 16; ++r) s[r] = 0.f;
            __builtin_amdgcn_s_setprio(1);
#pragma unroll
            for (int fc = 0; fc < 4; ++fc) {
                bf16x8 kf = *(const bf16x8*)&Kt[(kt * 32 + m32) * KS + fc * 16 + hi * 8];
                s = __builtin_amdgcn_mfma_f32_32x32x16_bf16(kf, qf[fc], s, 0, 0, 0);
            }
            __builtin_amdgcn_s_setprio(0);
            unsigned P[8];
#pragma unroll
            for (int m = 0; m < 8; ++m) {
                union { bf16x2 h; unsigned u; } pk;
                pk.h[0] = (__bf16)fmaxf(s[2 * m], 0.f);
                pk.h[1] = (__bf16)fmaxf(s[2 * m + 1], 0.f);
                P[m] = pk.u;
            }
            asm("v_permlane32_swap_b32 %0, %1" : "+v"(P[0]), "+v"(P[2]));
            asm("v_permlane32_swap_b32 %0, %1" : "+v"(P[1]), "+v"(P[3]));
            asm("v_permlane32_swap_b32 %0, %1" : "+v"(P[4]), "+v"(P[6]));
            asm("v_permlane32_swap_b32 %0, %1" : "+v"(P[5]), "+v"(P[7]));
            union { unsigned u[4]; bf16x8 v; } lo, hiu;
            lo.u[0]  = P[0]; lo.u[1]  = P[1]; lo.u[2]  = P[2]; lo.u[3]  = P[3];
            hiu.u[0] = P[4]; hiu.u[1] = P[5]; hiu.u[2] = P[6]; hiu.u[3] = P[7];
            ps[kt * 2]     = lo.v;
            ps[kt * 2 + 1] = hiu.v;
        }

        // ---- PV: Oᵀ[f][q]; A = Gt rows (f), k-dim = keys ----
        __builtin_amdgcn_s_setprio(1);
#pragma unroll
        for (int ft = 0; ft < 2; ++ft)
#pragma unroll
            for (int kt = 0; kt < 2; ++kt)
#pragma unroll
                for (int kc = 0; kc < 2; ++kc) {
                    bf16x8 gfr = *(const bf16x8*)&Gt[(ft * 32 + m32) * KS +
                                                     kt * 32 + kc * 16 + hi * 8];
                    oacc[ft] = __builtin_amdgcn_mfma_f32_32x32x16_bf16(
                        gfr, ps[kt * 2 + kc], oacc[ft], 0, 0, 0);
                }
        __builtin_amdgcn_s_setprio(0);
    }

    // Epilogue: f = ft*32+(r&3)+8*(r>>2)+4*hi, q = q0+wave*32+m32
    const int q = q0 + wave * 32 + m32;
#pragma unroll
    for (int ft = 0; ft < 2; ++ft)
#pragma unroll
        for (int r = 0; r < 16; ++r) {
            int f = ft * 32 + (r & 3) + 8 * (r >> 2) + 4 * hi;
            unsafeAtomicAdd(&out[((size_t)t * F + f) * (size_t)N + q], oacc[ft][r]);
        }
}

// ---------------------------------------------------------------------------
extern "C" void kernel_launch(void* const* d_in, const int* in_sizes, int n_in,
                              void* d_out, int out_size, void* d_ws, size_t ws_size,
                              hipStream_t stream) {
    const float* x1 = (const float*)d_in[0];
    const float* x2 = (const float*)d_in[1];
    const float* W1 = (const float*)d_in[2];
    const float* b1 = (const float*)d_in[3];
    const float* W2 = (const float*)d_in[4];
    const float* b2 = (const float*)d_in[5];
    const float* W3 = (const float*)d_in[6];
    const float* b3 = (const float*)d_in[7];
    float* out = (float*)d_out;

    __bf16* Qb = (__bf16*)d_ws;
    __bf16* Kb = Qb + (size_t)T * N * F;
    __bf16* Gw = Kb + (size_t)T * N * F;
    __bf16* Wb = Gw + (size_t)T * N * F;

    setup_kernel<<<dim3(T * F * N / 4 / 256), dim3(256), 0, stream>>>(
        W1, W2, W3, Wb, out);
    proj_kernel<<<dim3(T * (N / 64), 3), dim3(256), 0, stream>>>(
        x1, x2, Wb, b1, b2, b3, Qb, Kb, Gw);
    attn_kernel<<<dim3(T * 32 * KSPLIT), dim3(256), 0, stream>>>(Qb, Kb, Gw, out);
}

// Round 8
// 151.910 us; speedup vs baseline: 1.1111x; 1.1111x over previous
//
#include <hip/hip_runtime.h>
#include <hip/hip_bf16.h>

// Problem constants (B=1 folded out)
constexpr int T = 8;     // frames
constexpr int C = 128;   // input channels
constexpr int N = 4096;  // H*W positions
constexpr int F = 64;    // feature dim

typedef __bf16 bf16x8 __attribute__((ext_vector_type(8)));
typedef __bf16 bf16x4 __attribute__((ext_vector_type(4)));
typedef __bf16 bf16x2 __attribute__((ext_vector_type(2)));
typedef float  f32x4  __attribute__((ext_vector_type(4)));
typedef float  f32x16 __attribute__((ext_vector_type(16)));

// ---------------------------------------------------------------------------
// Kernel 0 (fused): zero d_out (attn accumulates with atomics) + convert
// W1/W2/W3 (fp32 [F][C]) to bf16 packed [3][F][C].
// ---------------------------------------------------------------------------
__global__ __launch_bounds__(256) void setup_kernel(
    const float* __restrict__ W1, const float* __restrict__ W2,
    const float* __restrict__ W3, __bf16* __restrict__ Wb,
    float* __restrict__ out)
{
    int i = blockIdx.x * 256 + threadIdx.x;
    ((f32x4*)out)[i] = (f32x4){0.f, 0.f, 0.f, 0.f};
    if (i < 3 * F * C) {
        int p = i >> 13, r = i & 8191;
        const float* W = (p == 0) ? W1 : (p == 1) ? W2 : W3;
        Wb[i] = (__bf16)W[r];
    }
}

// ---------------------------------------------------------------------------
// Kernel 1: projections, split by projection (R7 version, residual-neutral).
// blockIdx.y = pj in {0:Q, 1:K, 2:G}; grid (512, 3).
//   Q,K: D[m=f][n'=n] = W · X^T -> [n][F], b64 stores over f
//   G:   D[m=n][n'=f] = X^T · W3 -> [f][N], b64 stores over n
// ---------------------------------------------------------------------------
__global__ __launch_bounds__(256) void proj_kernel(
    const float* __restrict__ x1, const float* __restrict__ x2,
    const __bf16* __restrict__ Wb,
    const float* __restrict__ b1, const float* __restrict__ b2,
    const float* __restrict__ b3,
    __bf16* __restrict__ Qb, __bf16* __restrict__ Kb, __bf16* __restrict__ Gw)
{
    const int pj = blockIdx.y;        // 0=Q, 1=K, 2=G
    const int t  = blockIdx.x >> 6;
    const int nb = blockIdx.x & 63;
    const int n0 = nb * 64;

    constexpr int XS = 136;           // 272B rows (16B aligned)
    __shared__ __bf16 Xt[64 * XS];    // X^T tile: [n_local][c]

    const float* X = (pj == 1) ? x2 : x1;

    const int tid = threadIdx.x;
    const int ng  = tid & 15;         // n-block: n = ng*4 + j
    const int cgi = tid >> 4;         // c-group: c = cgi*4 (+64 per pass)

#pragma unroll
    for (int pass = 0; pass < 2; ++pass) {
        const int c0 = cgi * 4 + pass * 64;
        const size_t base = ((size_t)t * C + c0) * (size_t)N + n0 + ng * 4;
        f32x4 v[4];
#pragma unroll
        for (int i = 0; i < 4; ++i)
            v[i] = *(const f32x4*)&X[base + (size_t)i * N];
#pragma unroll
        for (int j = 0; j < 4; ++j) {
            bf16x4 o;
#pragma unroll
            for (int i = 0; i < 4; ++i) o[i] = (__bf16)v[i][j];
            *(bf16x4*)&Xt[(ng * 4 + j) * XS + c0] = o;
        }
    }
    __syncthreads();

    const int wave = tid >> 6, lane = tid & 63;
    const int quad = lane >> 4, l16 = lane & 15;

    bf16x8 a[4];
#pragma unroll
    for (int cc = 0; cc < 4; ++cc)
        a[cc] = *(const bf16x8*)&Xt[(wave * 16 + l16) * XS + cc * 32 + quad * 8];

    const __bf16* W = Wb + (size_t)pj * F * C;

    if (pj < 2) {
        // ---- Q or K: D[m=f][n'=n] = W · X^T ----
        const float* bias = pj ? b2 : b1;
        __bf16*      O    = pj ? Kb : Qb;

        f32x4 acc[4];
#pragma unroll
        for (int ft = 0; ft < 4; ++ft) acc[ft] = (f32x4){0.f, 0.f, 0.f, 0.f};
#pragma unroll
        for (int cc = 0; cc < 4; ++cc) {
#pragma unroll
            for (int ft = 0; ft < 4; ++ft) {
                bf16x8 wf = *(const bf16x8*)&W[(ft * 16 + l16) * C + cc * 32 + quad * 8];
                acc[ft] = __builtin_amdgcn_mfma_f32_16x16x32_bf16(wf, a[cc], acc[ft], 0, 0, 0);
            }
        }
        const int n = n0 + wave * 16 + l16;
#pragma unroll
        for (int ft = 0; ft < 4; ++ft) {
            const int f0 = ft * 16 + quad * 4;
            f32x4 bv = *(const f32x4*)&bias[f0];
            bf16x4 o;
#pragma unroll
            for (int r = 0; r < 4; ++r) o[r] = (__bf16)(acc[ft][r] + bv[r]);
            *(bf16x4*)&O[((size_t)t * N + n) * F + f0] = o;
        }
    } else {
        // ---- G: D[m=n][n'=f] = X^T · W3 ----
        f32x4 acc[4];
#pragma unroll
        for (int ft = 0; ft < 4; ++ft) acc[ft] = (f32x4){0.f, 0.f, 0.f, 0.f};
#pragma unroll
        for (int cc = 0; cc < 4; ++cc) {
#pragma unroll
            for (int ft = 0; ft < 4; ++ft) {
                bf16x8 wf = *(const bf16x8*)&W[(ft * 16 + l16) * C + cc * 32 + quad * 8];
                acc[ft] = __builtin_amdgcn_mfma_f32_16x16x32_bf16(a[cc], wf, acc[ft], 0, 0, 0);
            }
        }
        const int nr0 = n0 + wave * 16 + quad * 4;
#pragma unroll
        for (int ft = 0; ft < 4; ++ft) {
            const int f = ft * 16 + l16;
            const float bv = b3[f];
            bf16x4 o;
#pragma unroll
            for (int r = 0; r < 4; ++r) o[r] = (__bf16)(acc[ft][r] + bv);
            *(bf16x4*)&Gw[((size_t)t * F + f) * (size_t)N + nr0] = o;
        }
    }
}

// ---------------------------------------------------------------------------
// Kernel 2: O[t][f][q] += sum_key relu(Q[q]·K[key]) * G[key][f]
//
// v6: R4-verified per-wave pipeline (32 q/wave, 32x32x16 MFMA, in-register S
// via relu+pack+v_permlane32_swap, bank conflicts 0), now with 8 WAVES PER
// BLOCK (512 threads, 256 q) sharing each 64-key K/G tile. KSPLIT stays 4
// (atomic WRITE back to 32 MB). Grid 512 = 2 blocks/CU co-resident
// (__launch_bounds__(512,4) caps VGPR at 128): 16 waves/CU vs R4's ~7 —
// cross-wave interleave of S-chain / pack / PV / staging with no added HBM
// traffic. Per-thread staging halves (1 K + 1 G bf16x8 per tile).
// ---------------------------------------------------------------------------
constexpr int KSPLIT = 4;

__global__ __launch_bounds__(512, 4) void attn_kernel(
    const __bf16* __restrict__ Qb, const __bf16* __restrict__ Kb,
    const __bf16* __restrict__ Gw, float* __restrict__ out)
{
    const int ks = blockIdx.x & (KSPLIT - 1);
    const int qb = (blockIdx.x / KSPLIT) & 15;   // N/256 = 16 q-blocks
    const int t  = blockIdx.x / (KSPLIT * 16);
    const int q0 = qb * 256;

    constexpr int KS = 72;              // bf16 stride (144B rows, 16B aligned)
    __shared__ __bf16 Kt[64 * KS];      // K tile [key][f]
    __shared__ __bf16 Gt[64 * KS];      // G tile [f][key]

    const int tid = threadIdx.x, wave = tid >> 6, lane = tid & 63;
    const int m32 = lane & 31, hi = lane >> 5;

    // Q B-frags (32x32x16): lane holds Q[q = q0+wave*32+m32][f = fc*16+hi*8+j]
    bf16x8 qf[4];
    {
        const __bf16* qrow = &Qb[((size_t)t * N + q0 + wave * 32 + m32) * F + hi * 8];
#pragma unroll
        for (int fc = 0; fc < 4; ++fc)
            qf[fc] = *(const bf16x8*)(qrow + fc * 16);
    }

    f32x16 oacc[2];   // [f-tile]; D: col=q=m32, row=f=ft*32+(r&3)+8*(r>>2)+4*hi
#pragma unroll
    for (int ft = 0; ft < 2; ++ft)
#pragma unroll
        for (int r = 0; r < 16; ++r) oacc[ft][r] = 0.f;

    const int kb_lo = ks * (N / 64 / KSPLIT);
    const int kb_hi = kb_lo + (N / 64 / KSPLIT);

    // staging unit: 512 threads cover 64x64 bf16 exactly once per tile
    const int r8 = tid >> 3, c8 = (tid & 7) * 8;

    // prefetch tile kb_lo into registers
    bf16x8 kv, gv;
    {
        const int k0 = kb_lo * 64;
        kv = *(const bf16x8*)&Kb[((size_t)t * N + k0 + r8) * F + c8];
        gv = *(const bf16x8*)&Gw[((size_t)t * F + r8) * (size_t)N + k0 + c8];
    }

    for (int kb = kb_lo; kb < kb_hi; ++kb) {
        __syncthreads();   // previous tile's LDS reads done
        *(bf16x8*)&Kt[r8 * KS + c8] = kv;
        *(bf16x8*)&Gt[r8 * KS + c8] = gv;
        __syncthreads();

        if (kb + 1 < kb_hi) {   // prefetch next tile (overlaps with compute)
            const int k0 = (kb + 1) * 64;
            kv = *(const bf16x8*)&Kb[((size_t)t * N + k0 + r8) * F + c8];
            gv = *(const bf16x8*)&Gw[((size_t)t * F + r8) * (size_t)N + k0 + c8];
        }

        // ---- S + pack: per 32-key block, Sᵀ stays in registers ----
        bf16x8 ps[4];   // PV B-frags: ps[kt*2+kc] = keys kt*32+kc*16+hi*8+(0..7)
#pragma unroll
        for (int kt = 0; kt < 2; ++kt) {
            f32x16 s;
#pragma unroll
            for (int r = 0; r < 16; ++r) s[r] = 0.f;
            __builtin_amdgcn_s_setprio(1);
#pragma unroll
            for (int fc = 0; fc < 4; ++fc) {
                bf16x8 kf = *(const bf16x8*)&Kt[(kt * 32 + m32) * KS + fc * 16 + hi * 8];
                s = __builtin_amdgcn_mfma_f32_32x32x16_bf16(kf, qf[fc], s, 0, 0, 0);
            }
            __builtin_amdgcn_s_setprio(0);
            unsigned P[8];
#pragma unroll
            for (int m = 0; m < 8; ++m) {
                union { bf16x2 h; unsigned u; } pk;
                pk.h[0] = (__bf16)fmaxf(s[2 * m], 0.f);
                pk.h[1] = (__bf16)fmaxf(s[2 * m + 1], 0.f);
                P[m] = pk.u;
            }
            asm("v_permlane32_swap_b32 %0, %1" : "+v"(P[0]), "+v"(P[2]));
            asm("v_permlane32_swap_b32 %0, %1" : "+v"(P[1]), "+v"(P[3]));
            asm("v_permlane32_swap_b32 %0, %1" : "+v"(P[4]), "+v"(P[6]));
            asm("v_permlane32_swap_b32 %0, %1" : "+v"(P[5]), "+v"(P[7]));
            union { unsigned u[4]; bf16x8 v; } lo, hiu;
            lo.u[0]  = P[0]; lo.u[1]  = P[1]; lo.u[2]  = P[2]; lo.u[3]  = P[3];
            hiu.u[0] = P[4]; hiu.u[1] = P[5]; hiu.u[2] = P[6]; hiu.u[3] = P[7];
            ps[kt * 2]     = lo.v;
            ps[kt * 2 + 1] = hiu.v;
        }

        // ---- PV: Oᵀ[f][q]; A = Gt rows (f), k-dim = keys ----
        __builtin_amdgcn_s_setprio(1);
#pragma unroll
        for (int ft = 0; ft < 2; ++ft)
#pragma unroll
            for (int kt = 0; kt < 2; ++kt)
#pragma unroll
                for (int kc = 0; kc < 2; ++kc) {
                    bf16x8 gfr = *(const bf16x8*)&Gt[(ft * 32 + m32) * KS +
                                                     kt * 32 + kc * 16 + hi * 8];
                    oacc[ft] = __builtin_amdgcn_mfma_f32_32x32x16_bf16(
                        gfr, ps[kt * 2 + kc], oacc[ft], 0, 0, 0);
                }
        __builtin_amdgcn_s_setprio(0);
    }

    // Epilogue: f = ft*32+(r&3)+8*(r>>2)+4*hi, q = q0+wave*32+m32
    const int q = q0 + wave * 32 + m32;
#pragma unroll
    for (int ft = 0; ft < 2; ++ft)
#pragma unroll
        for (int r = 0; r < 16; ++r) {
            int f = ft * 32 + (r & 3) + 8 * (r >> 2) + 4 * hi;
            unsafeAtomicAdd(&out[((size_t)t * F + f) * (size_t)N + q], oacc[ft][r]);
        }
}

// ---------------------------------------------------------------------------
extern "C" void kernel_launch(void* const* d_in, const int* in_sizes, int n_in,
                              void* d_out, int out_size, void* d_ws, size_t ws_size,
                              hipStream_t stream) {
    const float* x1 = (const float*)d_in[0];
    const float* x2 = (const float*)d_in[1];
    const float* W1 = (const float*)d_in[2];
    const float* b1 = (const float*)d_in[3];
    const float* W2 = (const float*)d_in[4];
    const float* b2 = (const float*)d_in[5];
    const float* W3 = (const float*)d_in[6];
    const float* b3 = (const float*)d_in[7];
    float* out = (float*)d_out;

    __bf16* Qb = (__bf16*)d_ws;
    __bf16* Kb = Qb + (size_t)T * N * F;
    __bf16* Gw = Kb + (size_t)T * N * F;
    __bf16* Wb = Gw + (size_t)T * N * F;

    setup_kernel<<<dim3(T * F * N / 4 / 256), dim3(256), 0, stream>>>(
        W1, W2, W3, Wb, out);
    proj_kernel<<<dim3(T * (N / 64), 3), dim3(256), 0, stream>>>(
        x1, x2, Wb, b1, b2, b3, Qb, Kb, Gw);
    attn_kernel<<<dim3(T * 16 * KSPLIT), dim3(512), 0, stream>>>(Qb, Kb, Gw, out);
}